// Round 9
// baseline (22.395 us; speedup 1.0000x reference)
//
#include <hip/hip_runtime.h>

// DirectVolumeStratifiedFrontToBackRenderer — MI355X
// Ray-march 256x256 rays x 320 samples through a 256^3 f32 volume.
// alpha = const 0.1 inside the [-1,1]^3 local cube (f32: 1-0.1f+1e-10==0.9f,
// 1+1e-10==1.0f) so outside samples are exact no-ops and transmittance before
// sample i is 0.9^(i-i0) on the exact inside interval [i0,i1] (monotone in i).
// Output = standardize + minmax at out[w*256+h].
//
// R8: two independent gather->lerp chains per thread (chunks g and g+8 of a
// 16-way split, KMAX=48 -> <=3 iters each, fully unrolled). R7 showed time ~
// samples x exposed latency with nothing saturated; fine-grained 2-chain ILP
// halves the dependent critical path (R4's failure was BATCHED loads, not
// ILP itself). Gathers unconditional (coords clamped both sides -> memory
// safe past interval end), accumulate predicated -> no exec-mask
// serialization between chains.

#define G    8    // waves per ray-strip (threads per ray = 2 chains x 8)
#define BLK  512  // G waves of 64 pixels
#define KMAX 48   // truncation: max inside samples per ray (0.9^48 ~= 6.4e-3)

struct Partial { double sum; double sq; float mn; float mx; };

__global__ __launch_bounds__(BLK) void render_kernel(
    const float* __restrict__ vol,
    const float* __restrict__ camR,
    const float* __restrict__ camT,
    float* __restrict__ gray,
    Partial* __restrict__ parts)
{
    const int lane = threadIdx.x & 63;
    const int g    = threadIdx.x >> 6;

    // heavy-first remap: rank r -> row h, center-out (127,128,126,129,...)
    const int r      = blockIdx.x >> 2;       // 0..255
    const int sstrip = blockIdx.x & 3;        // 4 strips of 64 pixels per row
    const int h      = (r & 1) ? (128 + (r >> 1)) : (127 - (r >> 1));
    const int w      = (sstrip << 6) + lane;

    // camera (B=1). Rt = R^T; origin = -Rt*T; dir = Rt*dir_cam.
    const float R00=camR[0],R01=camR[1],R02=camR[2];
    const float R10=camR[3],R11=camR[4],R12=camR[5];
    const float R20=camR[6],R21=camR[7],R22=camR[8];
    const float T0=camT[0],T1=camT[1],T2=camT[2];

    const float ox = -(R00*T0 + R10*T1 + R20*T2);
    const float oy = -(R01*T0 + R11*T1 + R21*T2);
    const float oz = -(R02*T0 + R12*T1 + R22*T2);

    const float FOVT = 0.57735026918962576f;   // tan(30 deg)
    const float gx = -1.0f + w * (2.0f/255.0f);
    const float gy = -1.0f + h * (2.0f/255.0f);
    const float dcx = gx*FOVT, dcy = gy*FOVT;  // dcz = 1

    const float dx = R00*dcx + R10*dcy + R20;
    const float dy = R01*dcx + R11*dcy + R21;
    const float dz = R02*dcx + R12*dcy + R22;

    // half = 255 * (3/256) * 0.5 = 1.494140625 (exact in f32)
    const float H = 1.494140625f;
    const float inv_half = (float)(1.0 / 1.494140625);
    const float DSTEP = 4.0f / 319.0f;
    const float INV_DSTEP = 319.0f / 4.0f;

    __shared__ int   s_i0[64], s_i1[64];
    __shared__ float s_part[G][64];

    // ---- interval [i0,i1] computed once per pixel (wave 0), shared via LDS ----
    if (g == 0) {
        float tlo = 2.0f;
        float thi = 6.0f;
        bool nonempty = true;
        const float o3[3] = {ox, oy, oz};
        const float d3[3] = {dx, dy, dz};
        #pragma unroll
        for (int a = 0; a < 3; ++a) {
            const float o = o3[a], dc = d3[a];
            if (fabsf(dc) > 1e-8f) {
                const float rr = 1.0f / dc;
                const float ta = (-H - o) * rr;
                const float tb = ( H - o) * rr;
                tlo = fmaxf(tlo, fminf(ta, tb));
                thi = fminf(thi, fmaxf(ta, tb));
            } else if (fabsf(o) > H) {
                nonempty = false;
            }
        }

        // exact inside predicate — same forms as the validated R1-R7 kernels
        auto inside_i = [&](int i) -> bool {
            const float d = 2.0f + (float)i * DSTEP;
            const float px = fmaf(dx, d, ox) * inv_half;
            const float py = fmaf(dy, d, oy) * inv_half;
            const float pz = fmaf(dz, d, oz) * inv_half;
            return fabsf(px) <= 1.0f && fabsf(py) <= 1.0f && fabsf(pz) <= 1.0f;
        };

        int i0 = 0, i1 = -1;
        if (nonempty && thi >= tlo) {
            int ilo = max(0,   (int)floorf((tlo - 2.0f) * INV_DSTEP) - 2);
            int ihi = min(319, (int)ceilf ((thi - 2.0f) * INV_DSTEP) + 2);
            i0 = ilo; while (i0 <= ihi && !inside_i(i0)) ++i0;
            i1 = ihi; while (i1 >= i0 && !inside_i(i1)) --i1;
            if (i0 > ihi) { i0 = 0; i1 = -1; }
            // truncate the exponentially-weighted tail (weight <= 0.9^KMAX)
            i1 = min(i1, i0 + (KMAX - 1));
        }
        s_i0[lane] = i0;
        s_i1[lane] = i1;
    }
    __syncthreads();

    const int i0 = s_i0[lane];
    const int i1 = s_i1[lane];

    // 16-way contiguous split; thread g owns chunks g (chain A) and g+8 (B).
    const int len  = i1 - i0 + 1;                  // 0..KMAX
    const int c16  = (len + 15) >> 4;              // ceil(len/16), 0..3
    const int jA   = g * c16;
    const int jB   = (g + 8) * c16;
    const int cntA = min(c16, max(len - jA, 0));
    const int cntB = min(c16, max(len - jB, 0));

    // start weights: wA = 0.9^jA = (0.9^c16)^g, wB = wA * (0.9^c16)^8
    float wc = 1.0f;
    for (int j = 0; j < c16; ++j) wc *= 0.9f;      // <=3 mults
    float wA = 1.0f;
    for (int j = 0; j < g; ++j) wA *= wc;          // <=7 mults
    float wc8 = wc * wc; wc8 *= wc8; wc8 *= wc8;   // wc^8
    float wB = wA * wc8;

    // incremental affine voxel coords: f = X*SC + 127.5, X = fmaf(d_,t,o_)
    const float SC = inv_half * 127.5f;
    const float sx = dx * DSTEP * SC;
    const float sy = dy * DSTEP * SC;
    const float sz = dz * DSTEP * SC;
    const float d0A = 2.0f + (float)(i0 + jA) * DSTEP;
    const float d0B = 2.0f + (float)(i0 + jB) * DSTEP;
    float fxA = fmaf(fmaf(dx, d0A, ox), SC, 127.5f);
    float fyA = fmaf(fmaf(dy, d0A, oy), SC, 127.5f);
    float fzA = fmaf(fmaf(dz, d0A, oz), SC, 127.5f);
    float fxB = fmaf(fmaf(dx, d0B, ox), SC, 127.5f);
    float fyB = fmaf(fmaf(dy, d0B, oy), SC, 127.5f);
    float fzB = fmaf(fmaf(dz, d0B, oz), SC, 127.5f);

    float sAcc = 0.0f, sBcc = 0.0f;

    #pragma unroll 3
    for (int k = 0; k < c16; ++k) {
        // ---- chain A addresses (coords clamped both sides: safe past end) ----
        const float xfA = floorf(fxA), yfA = floorf(fyA), zfA = floorf(fzA);
        const int xbA = min(max((int)xfA, 0), 254);
        const int y0A = min(max((int)yfA, 0), 255);
        const int z0A = min(max((int)zfA, 0), 255);
        const int y1A = min(y0A + 1, 255);
        const int z1A = min(z0A + 1, 255);
        const float wxA = fxA - (float)xbA, wyA = fyA - yfA, wzA = fzA - zfA;
        const int a00 = (z0A << 16) + (y0A << 8) + xbA;
        const int a01 = (z0A << 16) + (y1A << 8) + xbA;
        const int a10 = (z1A << 16) + (y0A << 8) + xbA;
        const int a11 = (z1A << 16) + (y1A << 8) + xbA;
        // ---- chain B addresses ----
        const float xfB = floorf(fxB), yfB = floorf(fyB), zfB = floorf(fzB);
        const int xbB = min(max((int)xfB, 0), 254);
        const int y0B = min(max((int)yfB, 0), 255);
        const int z0B = min(max((int)zfB, 0), 255);
        const int y1B = min(y0B + 1, 255);
        const int z1B = min(z0B + 1, 255);
        const float wxB = fxB - (float)xbB, wyB = fyB - yfB, wzB = fzB - zfB;
        const int b00 = (z0B << 16) + (y0B << 8) + xbB;
        const int b01 = (z0B << 16) + (y1B << 8) + xbB;
        const int b10 = (z1B << 16) + (y0B << 8) + xbB;
        const int b11 = (z1B << 16) + (y1B << 8) + xbB;
        // ---- 8 independent gathers ----
        const float2 A00 = *reinterpret_cast<const float2*>(vol + a00);
        const float2 A01 = *reinterpret_cast<const float2*>(vol + a01);
        const float2 A10 = *reinterpret_cast<const float2*>(vol + a10);
        const float2 A11 = *reinterpret_cast<const float2*>(vol + a11);
        const float2 B00 = *reinterpret_cast<const float2*>(vol + b00);
        const float2 B01 = *reinterpret_cast<const float2*>(vol + b01);
        const float2 B10 = *reinterpret_cast<const float2*>(vol + b10);
        const float2 B11 = *reinterpret_cast<const float2*>(vol + b11);
        fxA += sx; fyA += sy; fzA += sz;
        fxB += sx; fyB += sy; fzB += sz;
        // ---- chain A lerp ----
        const float cA00 = fmaf(wxA, A00.y - A00.x, A00.x);
        const float cA01 = fmaf(wxA, A01.y - A01.x, A01.x);
        const float cA10 = fmaf(wxA, A10.y - A10.x, A10.x);
        const float cA11 = fmaf(wxA, A11.y - A11.x, A11.x);
        const float cA0 = fmaf(wyA, cA01 - cA00, cA00);
        const float cA1 = fmaf(wyA, cA11 - cA10, cA10);
        const float vA  = fmaf(wzA, cA1 - cA0, cA0);
        // ---- chain B lerp ----
        const float cB00 = fmaf(wxB, B00.y - B00.x, B00.x);
        const float cB01 = fmaf(wxB, B01.y - B01.x, B01.x);
        const float cB10 = fmaf(wxB, B10.y - B10.x, B10.x);
        const float cB11 = fmaf(wxB, B11.y - B11.x, B11.x);
        const float cB0 = fmaf(wyB, cB01 - cB00, cB00);
        const float cB1 = fmaf(wyB, cB11 - cB10, cB10);
        const float vB  = fmaf(wzB, cB1 - cB0, cB0);
        // ---- predicated accumulate (no exec-mask serialization) ----
        const float eA = (k < cntA) ? wA : 0.0f;
        const float eB = (k < cntB) ? wB : 0.0f;
        sAcc = fmaf(eA, vA, sAcc);
        sBcc = fmaf(eB, vB, sBcc);
        wA *= 0.9f;
        wB *= 0.9f;
    }

    s_part[g][lane] = sAcc + sBcc;
    __syncthreads();

    if (threadIdx.x < 64) {
        const int l = threadIdx.x;
        float total = 0.0f;
        #pragma unroll
        for (int q = 0; q < G; ++q) total += s_part[q][l];
        total *= 0.1f;

        const int ww = (sstrip << 6) + l;
        // screen = transpose(rgba,(0,3,2,1)) -> out[w*256 + h]
        gray[ww * 256 + h] = total;

        // per-block stats partial (wave-wide shuffle reduce over 64 totals)
        double sum = (double)total;
        double sq  = (double)total * (double)total;
        float  mn = total, mx = total;
        #pragma unroll
        for (int off = 32; off > 0; off >>= 1) {
            sum += __shfl_xor(sum, off);
            sq  += __shfl_xor(sq,  off);
            mn = fminf(mn, __shfl_xor(mn, off));
            mx = fmaxf(mx, __shfl_xor(mx, off));
        }
        if (l == 0) {
            parts[blockIdx.x].sum = sum;
            parts[blockIdx.x].sq  = sq;
            parts[blockIdx.x].mn  = mn;
            parts[blockIdx.x].mx  = mx;
        }
    }
}

__global__ __launch_bounds__(1024) void finalize_kernel(
    float* __restrict__ gray, const Partial* __restrict__ parts)
{
    const int tid = threadIdx.x;

    // each block redundantly reduces the 1024 render-block partials
    Partial p = parts[tid];
    double sum = p.sum, sq = p.sq;
    float  mn = p.mn,  mx = p.mx;
    #pragma unroll
    for (int off = 32; off > 0; off >>= 1) {
        sum += __shfl_xor(sum, off);
        sq  += __shfl_xor(sq,  off);
        mn = fminf(mn, __shfl_xor(mn, off));
        mx = fmaxf(mx, __shfl_xor(mx, off));
    }
    __shared__ double s_sum[16], s_sq[16];
    __shared__ float  s_mn[16],  s_mx[16];
    const int wid = tid >> 6;
    if ((tid & 63) == 0) { s_sum[wid]=sum; s_sq[wid]=sq; s_mn[wid]=mn; s_mx[wid]=mx; }
    __syncthreads();

    __shared__ float fpar[4];
    if (tid == 0) {
        double S = 0.0, Q = 0.0;
        float MN = 3.4e38f, MX = -3.4e38f;
        #pragma unroll
        for (int q = 0; q < 16; ++q) {
            S += s_sum[q]; Q += s_sq[q];
            MN = fminf(MN, s_mn[q]); MX = fmaxf(MX, s_mx[q]);
        }
        const double N = 65536.0;
        const double mean = S / N;
        double var = (Q - S * S / N) / (N - 1.0);
        if (var < 0.0) var = 0.0;
        fpar[0] = (float)mean;
        fpar[1] = (float)sqrt(var) + 1e-8f;    // std(ddof=1) + EPS
        fpar[2] = MN;
        fpar[3] = MX;
    }
    __syncthreads();

    const float mean = fpar[0], sd = fpar[1];
    const float mnv = fpar[2],  mxv = fpar[3];
    const int idx = blockIdx.x * 1024 + tid;
    const float z    = (gray[idx] - mean) / sd;
    const float zmin = (mnv - mean) / sd;
    const float zmax = (mxv - mean) / sd;
    gray[idx] = (z - zmin + 1e-8f) / (zmax - zmin + 1e-8f);
}

extern "C" void kernel_launch(void* const* d_in, const int* in_sizes, int n_in,
                              void* d_out, int out_size, void* d_ws, size_t ws_size,
                              hipStream_t stream)
{
    const float* vol  = (const float*)d_in[0];   // (1,1,256,256,256) f32
    const float* camR = (const float*)d_in[1];   // (1,3,3)
    const float* camT = (const float*)d_in[2];   // (1,3)
    float* out = (float*)d_out;                  // 65536 f32, [w*256+h]
    Partial* parts = (Partial*)d_ws;             // 1024 * 24 B scratch

    render_kernel<<<dim3(1024), dim3(BLK), 0, stream>>>(vol, camR, camT, out, parts);
    finalize_kernel<<<dim3(64), dim3(1024), 0, stream>>>(out, parts);
}

// Round 10
// 17.724 us; speedup vs baseline: 1.2636x; 1.2636x over previous
//
#include <hip/hip_runtime.h>

// DirectVolumeStratifiedFrontToBackRenderer — MI355X
// Ray-march 256x256 rays x 320 samples through a 256^3 f32 volume.
// alpha = const 0.1 inside the [-1,1]^3 local cube (f32: 1-0.1f+1e-10==0.9f,
// 1+1e-10==1.0f) so outside samples are exact no-ops and transmittance before
// sample i is 0.9^(i-i0) on the exact inside interval [i0,i1] (monotone in i).
//
// Output algebra: out = (std - std.min + EPS)/(std.max - std.min + EPS) with
// std = (g - mean)/sd  collapses to  (g - mn + EPS*sd)/(mx - mn + EPS*sd);
// EPS*sd ~ 5e-10 is far below f32 resolution of the result -> only min/max
// of gray are needed (mean/std cancel). Written at out[w*256+h].
//
// R9: revert R8's 2-chain ILP (unconditional gathers wasted memory work,
// +14%). Back to R7 structure plus:
//  - XCD-band swizzle: band = bid&7 -> rows [band*32, band*32+32). HW round-
//    robins blocks over the 8 XCDs, so each XCD works one contiguous row
//    band whose marched tube (~1.3 MB) fits its 4 MB L2. Gathers are
//    MSHR-throughput-bound (~30 lines/wave-iter); throughput ~ slots/latency,
//    so L3->L2 latency cut is a direct win.
//  - min/max-only stats (float2 partials, no doubles/sum/sq).
//  - exp2f start weights (replaces divergent mult loops).

#define G    8    // threads per ray
#define BLK  512  // G waves of 64 pixels
#define KMAX 48   // truncation: max inside samples per ray (0.9^48 ~= 6.4e-3)

__global__ __launch_bounds__(BLK) void render_kernel(
    const float* __restrict__ vol,
    const float* __restrict__ camR,
    const float* __restrict__ camT,
    float* __restrict__ gray,
    float2* __restrict__ parts)
{
    const int lane = threadIdx.x & 63;
    const int g    = threadIdx.x >> 6;

    // XCD-band swizzle: blocks with bid%8==c land on XCD c (round-robin HW
    // dispatch); give each XCD one contiguous 32-row band for L2 locality.
    const int band   = blockIdx.x & 7;
    const int idx    = blockIdx.x >> 3;        // 0..127
    const int h      = (band << 5) + (idx >> 2);
    const int sstrip = idx & 3;                // 4 strips of 64 pixels per row
    const int w      = (sstrip << 6) + lane;

    // camera (B=1). Rt = R^T; origin = -Rt*T; dir = Rt*dir_cam.
    const float R00=camR[0],R01=camR[1],R02=camR[2];
    const float R10=camR[3],R11=camR[4],R12=camR[5];
    const float R20=camR[6],R21=camR[7],R22=camR[8];
    const float T0=camT[0],T1=camT[1],T2=camT[2];

    const float ox = -(R00*T0 + R10*T1 + R20*T2);
    const float oy = -(R01*T0 + R11*T1 + R21*T2);
    const float oz = -(R02*T0 + R12*T1 + R22*T2);

    const float FOVT = 0.57735026918962576f;   // tan(30 deg)
    const float gx = -1.0f + w * (2.0f/255.0f);
    const float gy = -1.0f + h * (2.0f/255.0f);
    const float dcx = gx*FOVT, dcy = gy*FOVT;  // dcz = 1

    const float dx = R00*dcx + R10*dcy + R20;
    const float dy = R01*dcx + R11*dcy + R21;
    const float dz = R02*dcx + R12*dcy + R22;

    // half = 255 * (3/256) * 0.5 = 1.494140625 (exact in f32)
    const float H = 1.494140625f;
    const float inv_half = (float)(1.0 / 1.494140625);
    const float DSTEP = 4.0f / 319.0f;
    const float INV_DSTEP = 319.0f / 4.0f;

    __shared__ int   s_i0[64], s_i1[64];
    __shared__ float s_part[G][64];

    // ---- interval [i0,i1] computed once per pixel (wave 0), shared via LDS ----
    if (g == 0) {
        float tlo = 2.0f;
        float thi = 6.0f;
        bool nonempty = true;
        const float o3[3] = {ox, oy, oz};
        const float d3[3] = {dx, dy, dz};
        #pragma unroll
        for (int a = 0; a < 3; ++a) {
            const float o = o3[a], dc = d3[a];
            if (fabsf(dc) > 1e-8f) {
                const float rr = 1.0f / dc;
                const float ta = (-H - o) * rr;
                const float tb = ( H - o) * rr;
                tlo = fmaxf(tlo, fminf(ta, tb));
                thi = fminf(thi, fmaxf(ta, tb));
            } else if (fabsf(o) > H) {
                nonempty = false;
            }
        }

        // exact inside predicate — same forms as the validated R1-R8 kernels
        auto inside_i = [&](int i) -> bool {
            const float d = 2.0f + (float)i * DSTEP;
            const float px = fmaf(dx, d, ox) * inv_half;
            const float py = fmaf(dy, d, oy) * inv_half;
            const float pz = fmaf(dz, d, oz) * inv_half;
            return fabsf(px) <= 1.0f && fabsf(py) <= 1.0f && fabsf(pz) <= 1.0f;
        };

        int i0 = 0, i1 = -1;
        if (nonempty && thi >= tlo) {
            int ilo = max(0,   (int)floorf((tlo - 2.0f) * INV_DSTEP) - 2);
            int ihi = min(319, (int)ceilf ((thi - 2.0f) * INV_DSTEP) + 2);
            i0 = ilo; while (i0 <= ihi && !inside_i(i0)) ++i0;
            i1 = ihi; while (i1 >= i0 && !inside_i(i1)) --i1;
            if (i0 > ihi) { i0 = 0; i1 = -1; }
            // truncate the exponentially-weighted tail (weight <= 0.9^KMAX)
            i1 = min(i1, i0 + (KMAX - 1));
        }
        s_i0[lane] = i0;
        s_i1[lane] = i1;
    }
    __syncthreads();

    const int i0 = s_i0[lane];
    const int i1 = s_i1[lane];

    // contiguous split: thread g covers samples [i0+jstart, i0+jstart+cnt)
    const int len    = i1 - i0 + 1;                    // 0..KMAX
    const int chunk  = (len + G - 1) >> 3;             // ceil(len/8), 0..6
    const int jstart = g * chunk;
    const int cnt    = min(chunk, max(len - jstart, 0));

    // wgt = 0.9^jstart via exp2 (jstart <= 42; rel err ~1e-7, negligible)
    const float L2_9 = -0.15200309344504995f;          // log2(0.9)
    float wgt = exp2f(L2_9 * (float)jstart);

    // incremental affine voxel coords: f = X*SC + 127.5, X = fmaf(d_,t,o_)
    const float SC = inv_half * 127.5f;
    const float d0 = 2.0f + (float)(i0 + jstart) * DSTEP;
    float fx = fmaf(fmaf(dx, d0, ox), SC, 127.5f);
    float fy = fmaf(fmaf(dy, d0, oy), SC, 127.5f);
    float fz = fmaf(fmaf(dz, d0, oz), SC, 127.5f);
    const float sx = dx * DSTEP * SC;
    const float sy = dy * DSTEP * SC;
    const float sz = dz * DSTEP * SC;

    float s = 0.0f;
    #pragma unroll 2
    for (int k = 0; k < cnt; ++k) {
        const float x0f = floorf(fx), y0f = floorf(fy), z0f = floorf(fz);
        const float wy = fy - y0f, wz = fz - z0f;
        // paired-x base in [0,254]; wx = fx - xb is exact at both x edges.
        // (clamps also guard the ~5e-4 drift of the incremental coords)
        const int xb  = min(max((int)x0f, 0), 254);
        const float wx = fx - (float)xb;
        const int y0 = max((int)y0f, 0);
        const int z0 = max((int)z0f, 0);
        const int y1 = min(y0 + 1, 255);
        const int z1 = min(z0 + 1, 255);
        const int y0s = y0 << 8, y1s = y1 << 8;
        const int bz0 = (z0 << 16) + xb;
        const int bz1 = (z1 << 16) + xb;
        const float2 p00 = *reinterpret_cast<const float2*>(vol + (bz0 + y0s));
        const float2 p01 = *reinterpret_cast<const float2*>(vol + (bz0 + y1s));
        const float2 p10 = *reinterpret_cast<const float2*>(vol + (bz1 + y0s));
        const float2 p11 = *reinterpret_cast<const float2*>(vol + (bz1 + y1s));
        fx += sx; fy += sy; fz += sz;
        const float c00 = fmaf(wx, p00.y - p00.x, p00.x);
        const float c01 = fmaf(wx, p01.y - p01.x, p01.x);
        const float c10 = fmaf(wx, p10.y - p10.x, p10.x);
        const float c11 = fmaf(wx, p11.y - p11.x, p11.x);
        const float c0 = fmaf(wy, c01 - c00, c00);
        const float c1 = fmaf(wy, c11 - c10, c10);
        const float v  = fmaf(wz, c1 - c0, c0);
        s = fmaf(wgt, v, s);
        wgt *= 0.9f;
    }

    s_part[g][lane] = s;
    __syncthreads();

    if (threadIdx.x < 64) {
        const int l = threadIdx.x;
        float total = 0.0f;
        #pragma unroll
        for (int q = 0; q < G; ++q) total += s_part[q][l];
        total *= 0.1f;

        const int ww = (sstrip << 6) + l;
        // screen = transpose(rgba,(0,3,2,1)) -> out[w*256 + h]
        gray[ww * 256 + h] = total;

        // per-block min/max partial (wave-wide shuffle reduce)
        float mn = total, mx = total;
        #pragma unroll
        for (int off = 32; off > 0; off >>= 1) {
            mn = fminf(mn, __shfl_xor(mn, off));
            mx = fmaxf(mx, __shfl_xor(mx, off));
        }
        if (l == 0) {
            parts[blockIdx.x] = make_float2(mn, mx);
        }
    }
}

__global__ __launch_bounds__(1024) void finalize_kernel(
    float* __restrict__ gray, const float2* __restrict__ parts)
{
    const int tid = threadIdx.x;

    // each block redundantly reduces the 1024 render-block partials (8 KB)
    float2 p = parts[tid];
    float mn = p.x, mx = p.y;
    #pragma unroll
    for (int off = 32; off > 0; off >>= 1) {
        mn = fminf(mn, __shfl_xor(mn, off));
        mx = fmaxf(mx, __shfl_xor(mx, off));
    }
    __shared__ float s_mn[16], s_mx[16];
    const int wid = tid >> 6;
    if ((tid & 63) == 0) { s_mn[wid] = mn; s_mx[wid] = mx; }
    __syncthreads();

    __shared__ float fpar[2];
    if (tid == 0) {
        float MN = s_mn[0], MX = s_mx[0];
        #pragma unroll
        for (int q = 1; q < 16; ++q) {
            MN = fminf(MN, s_mn[q]);
            MX = fmaxf(MX, s_mx[q]);
        }
        fpar[0] = MN;
        fpar[1] = MX;
    }
    __syncthreads();

    // out = (g - mn + EPS*sd)/(mx - mn + EPS*sd); EPS*sd ~ 5e-10 -> use 1e-9
    const float mnv = fpar[0];
    const float den = fpar[1] - mnv + 1e-9f;
    const float rden = 1.0f / den;
    const int idx = blockIdx.x * 1024 + tid;
    gray[idx] = (gray[idx] - mnv + 1e-9f) * rden;
}

extern "C" void kernel_launch(void* const* d_in, const int* in_sizes, int n_in,
                              void* d_out, int out_size, void* d_ws, size_t ws_size,
                              hipStream_t stream)
{
    const float* vol  = (const float*)d_in[0];   // (1,1,256,256,256) f32
    const float* camR = (const float*)d_in[1];   // (1,3,3)
    const float* camT = (const float*)d_in[2];   // (1,3)
    float* out = (float*)d_out;                  // 65536 f32, [w*256+h]
    float2* parts = (float2*)d_ws;               // 1024 * 8 B scratch

    render_kernel<<<dim3(1024), dim3(BLK), 0, stream>>>(vol, camR, camT, out, parts);
    finalize_kernel<<<dim3(64), dim3(1024), 0, stream>>>(out, parts);
}

// Round 11
// 17.477 us; speedup vs baseline: 1.2814x; 1.0141x over previous
//
#include <hip/hip_runtime.h>

// DirectVolumeStratifiedFrontToBackRenderer — MI355X
// Ray-march 256x256 rays x 320 samples through a 256^3 f32 volume.
// alpha = const 0.1 inside the [-1,1]^3 local cube (f32: 1-0.1f+1e-10==0.9f,
// 1+1e-10==1.0f) so outside samples are exact no-ops and transmittance before
// sample i is 0.9^(i-i0) on the exact inside interval [i0,i1] (monotone in i).
//
// Output algebra: out = (std-std.min+EPS)/(std.max-std.min+EPS) with
// std=(g-mean)/sd collapses to (g-mn+EPS*sd)/(mx-mn+EPS*sd); EPS*sd ~ 5e-10
// is below f32 resolution -> only min/max needed. Written at out[w*256+h].
//
// R10: 2 blocks/CU (512 blocks x 512 thr) instead of 4. Per wave-iter the 4
// row-gathers touch ~28 L1 lines; ray advance ~1.07 voxel/sample means iter
// k's z1-rows == iter k+1's z0-rows (~half the lines reusable). At 32
// waves/CU the per-iteration L1 demand (~57 KB) thrashes the 32 KB L1; at 16
// waves/CU (~28 KB) the z-row reuse becomes L1 hits -> fewer L2/MSHR misses.
// Time model (validated R6-R9): time ~ lines x miss-latency / MSHR-slots, so
// line-miss cut is a direct win; TLP loss is free (MSHR saturated anyway).
// Block = half-row: 128 pixels x G=4 depth chunks (<=12 iters/thread).

#define G    4    // depth chunks per ray (threads per ray)
#define BLK  512  // 8 waves: strip = wave>>2 (2 strips of 64 px), gsub = wave&3
#define KMAX 48   // truncation: max inside samples per ray (0.9^48 ~= 6.4e-3)

__global__ __launch_bounds__(BLK) void render_kernel(
    const float* __restrict__ vol,
    const float* __restrict__ camR,
    const float* __restrict__ camT,
    float* __restrict__ gray,
    float2* __restrict__ parts)
{
    const int lane  = threadIdx.x & 63;
    const int wv    = threadIdx.x >> 6;   // 0..7
    const int strip = wv >> 2;            // 0..1 (64-pixel strip in half-row)
    const int gsub  = wv & 3;             // depth chunk 0..3

    // XCD-band swizzle (R9): bid%8 = band -> XCD via round-robin dispatch;
    // each XCD works rows [band*32, band*32+32) for L2 tube locality.
    const int band = blockIdx.x & 7;
    const int idx  = blockIdx.x >> 3;     // 0..63
    const int h    = (band << 5) + (idx >> 1);
    const int half = idx & 1;             // which 128-pixel half of the row
    const int p    = (strip << 6) + lane; // pixel in block, 0..127
    const int w    = (half << 7) + p;

    // camera (B=1). Rt = R^T; origin = -Rt*T; dir = Rt*dir_cam.
    const float R00=camR[0],R01=camR[1],R02=camR[2];
    const float R10=camR[3],R11=camR[4],R12=camR[5];
    const float R20=camR[6],R21=camR[7],R22=camR[8];
    const float T0=camT[0],T1=camT[1],T2=camT[2];

    const float ox = -(R00*T0 + R10*T1 + R20*T2);
    const float oy = -(R01*T0 + R11*T1 + R21*T2);
    const float oz = -(R02*T0 + R12*T1 + R22*T2);

    const float FOVT = 0.57735026918962576f;   // tan(30 deg)
    const float gx = -1.0f + w * (2.0f/255.0f);
    const float gy = -1.0f + h * (2.0f/255.0f);
    const float dcx = gx*FOVT, dcy = gy*FOVT;  // dcz = 1

    const float dx = R00*dcx + R10*dcy + R20;
    const float dy = R01*dcx + R11*dcy + R21;
    const float dz = R02*dcx + R12*dcy + R22;

    // half-extent = 255 * (3/256) * 0.5 = 1.494140625 (exact in f32)
    const float H = 1.494140625f;
    const float inv_half = (float)(1.0 / 1.494140625);
    const float DSTEP = 4.0f / 319.0f;
    const float INV_DSTEP = 319.0f / 4.0f;

    __shared__ int   s_i0[128], s_i1[128];
    __shared__ float s_part[G][128];
    __shared__ float s_mn2[2], s_mx2[2];

    // ---- interval [i0,i1] once per pixel: waves 0 (strip0) and 4 (strip1) ----
    if (gsub == 0) {
        float tlo = 2.0f;
        float thi = 6.0f;
        bool nonempty = true;
        const float o3[3] = {ox, oy, oz};
        const float d3[3] = {dx, dy, dz};
        #pragma unroll
        for (int a = 0; a < 3; ++a) {
            const float o = o3[a], dc = d3[a];
            if (fabsf(dc) > 1e-8f) {
                const float rr = 1.0f / dc;
                const float ta = (-H - o) * rr;
                const float tb = ( H - o) * rr;
                tlo = fmaxf(tlo, fminf(ta, tb));
                thi = fminf(thi, fmaxf(ta, tb));
            } else if (fabsf(o) > H) {
                nonempty = false;
            }
        }

        // exact inside predicate — same forms as the validated R1-R9 kernels
        auto inside_i = [&](int i) -> bool {
            const float d = 2.0f + (float)i * DSTEP;
            const float px = fmaf(dx, d, ox) * inv_half;
            const float py = fmaf(dy, d, oy) * inv_half;
            const float pz = fmaf(dz, d, oz) * inv_half;
            return fabsf(px) <= 1.0f && fabsf(py) <= 1.0f && fabsf(pz) <= 1.0f;
        };

        int i0 = 0, i1 = -1;
        if (nonempty && thi >= tlo) {
            int ilo = max(0,   (int)floorf((tlo - 2.0f) * INV_DSTEP) - 2);
            int ihi = min(319, (int)ceilf ((thi - 2.0f) * INV_DSTEP) + 2);
            i0 = ilo; while (i0 <= ihi && !inside_i(i0)) ++i0;
            i1 = ihi; while (i1 >= i0 && !inside_i(i1)) --i1;
            if (i0 > ihi) { i0 = 0; i1 = -1; }
            // truncate the exponentially-weighted tail (weight <= 0.9^KMAX)
            i1 = min(i1, i0 + (KMAX - 1));
        }
        s_i0[p] = i0;
        s_i1[p] = i1;
    }
    __syncthreads();

    const int i0 = s_i0[p];
    const int i1 = s_i1[p];

    // contiguous split: chunk gsub covers samples [i0+jstart, i0+jstart+cnt)
    const int len    = i1 - i0 + 1;                    // 0..KMAX
    const int chunk  = (len + G - 1) >> 2;             // ceil(len/4), 0..12
    const int jstart = gsub * chunk;
    const int cnt    = min(chunk, max(len - jstart, 0));

    // wgt = 0.9^jstart via exp2 (jstart <= 36; rel err ~1e-7, negligible)
    const float L2_9 = -0.15200309344504995f;          // log2(0.9)
    float wgt = exp2f(L2_9 * (float)jstart);

    // incremental affine voxel coords: f = X*SC + 127.5, X = fmaf(d_,t,o_)
    const float SC = inv_half * 127.5f;
    const float d0 = 2.0f + (float)(i0 + jstart) * DSTEP;
    float fx = fmaf(fmaf(dx, d0, ox), SC, 127.5f);
    float fy = fmaf(fmaf(dy, d0, oy), SC, 127.5f);
    float fz = fmaf(fmaf(dz, d0, oz), SC, 127.5f);
    const float sx = dx * DSTEP * SC;
    const float sy = dy * DSTEP * SC;
    const float sz = dz * DSTEP * SC;

    float s = 0.0f;
    #pragma unroll 2
    for (int k = 0; k < cnt; ++k) {
        const float x0f = floorf(fx), y0f = floorf(fy), z0f = floorf(fz);
        const float wy = fy - y0f, wz = fz - z0f;
        // paired-x base in [0,254]; wx = fx - xb is exact at both x edges.
        // (clamps also guard the ~5e-4 drift of the incremental coords)
        const int xb  = min(max((int)x0f, 0), 254);
        const float wx = fx - (float)xb;
        const int y0 = max((int)y0f, 0);
        const int z0 = max((int)z0f, 0);
        const int y1 = min(y0 + 1, 255);
        const int z1 = min(z0 + 1, 255);
        const int y0s = y0 << 8, y1s = y1 << 8;
        const int bz0 = (z0 << 16) + xb;
        const int bz1 = (z1 << 16) + xb;
        const float2 p00 = *reinterpret_cast<const float2*>(vol + (bz0 + y0s));
        const float2 p01 = *reinterpret_cast<const float2*>(vol + (bz0 + y1s));
        const float2 p10 = *reinterpret_cast<const float2*>(vol + (bz1 + y0s));
        const float2 p11 = *reinterpret_cast<const float2*>(vol + (bz1 + y1s));
        fx += sx; fy += sy; fz += sz;
        const float c00 = fmaf(wx, p00.y - p00.x, p00.x);
        const float c01 = fmaf(wx, p01.y - p01.x, p01.x);
        const float c10 = fmaf(wx, p10.y - p10.x, p10.x);
        const float c11 = fmaf(wx, p11.y - p11.x, p11.x);
        const float c0 = fmaf(wy, c01 - c00, c00);
        const float c1 = fmaf(wy, c11 - c10, c10);
        const float v  = fmaf(wz, c1 - c0, c0);
        s = fmaf(wgt, v, s);
        wgt *= 0.9f;
    }

    s_part[gsub][p] = s;
    __syncthreads();

    if (threadIdx.x < 128) {
        const int q = threadIdx.x;          // pixel in block (waves 0 and 1)
        float total = 0.0f;
        #pragma unroll
        for (int u = 0; u < G; ++u) total += s_part[u][q];
        total *= 0.1f;

        const int ww = (half << 7) + q;
        // screen = transpose(rgba,(0,3,2,1)) -> out[w*256 + h]
        gray[ww * 256 + h] = total;

        // per-block min/max partial (shuffle within each of the 2 waves)
        float mn = total, mx = total;
        #pragma unroll
        for (int off = 32; off > 0; off >>= 1) {
            mn = fminf(mn, __shfl_xor(mn, off));
            mx = fmaxf(mx, __shfl_xor(mx, off));
        }
        if ((q & 63) == 0) { s_mn2[q >> 6] = mn; s_mx2[q >> 6] = mx; }
    }
    __syncthreads();

    if (threadIdx.x == 0) {
        parts[blockIdx.x] = make_float2(fminf(s_mn2[0], s_mn2[1]),
                                        fmaxf(s_mx2[0], s_mx2[1]));
    }
}

__global__ __launch_bounds__(1024) void finalize_kernel(
    float* __restrict__ gray, const float2* __restrict__ parts)
{
    const int tid = threadIdx.x;

    // each block redundantly reduces the 512 render-block partials (4 KB)
    float mn = 3.4e38f, mx = -3.4e38f;
    if (tid < 512) {
        float2 p = parts[tid];
        mn = p.x; mx = p.y;
    }
    #pragma unroll
    for (int off = 32; off > 0; off >>= 1) {
        mn = fminf(mn, __shfl_xor(mn, off));
        mx = fmaxf(mx, __shfl_xor(mx, off));
    }
    __shared__ float s_mn[16], s_mx[16];
    const int wid = tid >> 6;
    if ((tid & 63) == 0) { s_mn[wid] = mn; s_mx[wid] = mx; }
    __syncthreads();

    __shared__ float fpar[2];
    if (tid == 0) {
        float MN = s_mn[0], MX = s_mx[0];
        #pragma unroll
        for (int q = 1; q < 8; ++q) {       // only waves 0..7 held partials
            MN = fminf(MN, s_mn[q]);
            MX = fmaxf(MX, s_mx[q]);
        }
        fpar[0] = MN;
        fpar[1] = MX;
    }
    __syncthreads();

    // out = (g - mn + EPS*sd)/(mx - mn + EPS*sd); EPS*sd ~ 5e-10 -> use 1e-9
    const float mnv = fpar[0];
    const float rden = 1.0f / (fpar[1] - mnv + 1e-9f);
    const int idx = blockIdx.x * 1024 + tid;
    gray[idx] = (gray[idx] - mnv + 1e-9f) * rden;
}

extern "C" void kernel_launch(void* const* d_in, const int* in_sizes, int n_in,
                              void* d_out, int out_size, void* d_ws, size_t ws_size,
                              hipStream_t stream)
{
    const float* vol  = (const float*)d_in[0];   // (1,1,256,256,256) f32
    const float* camR = (const float*)d_in[1];   // (1,3,3)
    const float* camT = (const float*)d_in[2];   // (1,3)
    float* out = (float*)d_out;                  // 65536 f32, [w*256+h]
    float2* parts = (float2*)d_ws;               // 512 * 8 B scratch

    render_kernel<<<dim3(512), dim3(BLK), 0, stream>>>(vol, camR, camT, out, parts);
    finalize_kernel<<<dim3(64), dim3(1024), 0, stream>>>(out, parts);
}